// Round 10
// baseline (3573.789 us; speedup 1.0000x reference)
//
#include <hip/hip_runtime.h>
#include <stdint.h>

#define M_TOT 8192
#define K_TOT 4096
#define N_TOT 11008

typedef __attribute__((ext_vector_type(4))) int i32x4;

// ---- pre-pass: A fp32 -> int8 with per-row scale (one block per row) ----
__global__ __launch_bounds__(256) void quant_a(const float* __restrict__ a,
                                               int8_t* __restrict__ o,
                                               float* __restrict__ sa) {
  const int row = blockIdx.x;
  const int tid = threadIdx.x;
  const float* ap = a + (size_t)row * K_TOT + tid * 16;
  float4 v[4];
#pragma unroll
  for (int i = 0; i < 4; ++i) v[i] = *(const float4*)(ap + i * 4);
  float m = 0.f;
#pragma unroll
  for (int i = 0; i < 4; ++i) {
    m = fmaxf(m, fmaxf(fmaxf(fabsf(v[i].x), fabsf(v[i].y)),
                       fmaxf(fabsf(v[i].z), fabsf(v[i].w))));
  }
#pragma unroll
  for (int off = 32; off >= 1; off >>= 1)
    m = fmaxf(m, __shfl_xor(m, off));
  __shared__ float red[4];
  if ((tid & 63) == 0) red[tid >> 6] = m;
  __syncthreads();
  float am = fmaxf(fmaxf(red[0], red[1]), fmaxf(red[2], red[3]));
  float inv = am > 0.f ? 127.0f / am : 0.f;
  if (tid == 0) sa[row] = am > 0.f ? am / 127.0f : 0.f;
  union { int8_t b[16]; int4 q; } rr;
#pragma unroll
  for (int i = 0; i < 4; ++i) {
    float4 w = v[i];
    rr.b[i * 4 + 0] = (int8_t)(int)rintf(w.x * inv);
    rr.b[i * 4 + 1] = (int8_t)(int)rintf(w.y * inv);
    rr.b[i * 4 + 2] = (int8_t)(int)rintf(w.z * inv);
    rr.b[i * 4 + 3] = (int8_t)(int)rintf(w.w * inv);
  }
  *(int4*)(o + (size_t)row * K_TOT + tid * 16) = rr.q;
}

// ---- pre-pass: W int32 (harness widened) -> int8 pack ----
__global__ __launch_bounds__(256) void pack_w(const int* __restrict__ w,
                                              int8_t* __restrict__ o, int n16) {
  int stride = gridDim.x * 256;
  for (int i = blockIdx.x * 256 + threadIdx.x; i < n16; i += stride) {
    const int4* p = (const int4*)(w + (size_t)i * 16);
    int4 v0 = p[0], v1 = p[1], v2 = p[2], v3 = p[3];
    int4 r;
    r.x = (v0.x & 0xff) | ((v0.y & 0xff) << 8) | ((v0.z & 0xff) << 16) | (v0.w << 24);
    r.y = (v1.x & 0xff) | ((v1.y & 0xff) << 8) | ((v1.z & 0xff) << 16) | (v1.w << 24);
    r.z = (v2.x & 0xff) | ((v2.y & 0xff) << 8) | ((v2.z & 0xff) << 16) | (v2.w << 24);
    r.w = (v3.x & 0xff) | ((v3.y & 0xff) << 8) | ((v3.z & 0xff) << 16) | (v3.w << 24);
    *(int4*)(o + (size_t)i * 16) = r;
  }
}

#define VM4 asm volatile("s_waitcnt vmcnt(4)" ::: "memory");
#define VM2 asm volatile("s_waitcnt vmcnt(2)" ::: "memory");
#define VM0 asm volatile("s_waitcnt vmcnt(0)" ::: "memory");
#define BAR __builtin_amdgcn_s_barrier();

// LDS: [op 0=A,1=B][buf][256 rows x 64 B] = 64 KiB total -> 2 blocks/CU
#define RD_A(BUF, MF) (*(const i32x4*)(lbase + ((BUF)*16384 + (MF)*1024) + va))
#define RD_B(BUF, NF) (*(const i32x4*)(lbase + ((BUF)*16384 + (NF)*1024) + vb))

// stage one 128-row x 64B half-panel (8 KiB): 512 threads x 16 B, linear dest
#define STG(OP, Q, BUF, SRC) \
  __builtin_amdgcn_global_load_lds( \
      (const __attribute__((address_space(1))) void*)((SRC) + (size_t)(Q)*128*K_TOT), \
      (__attribute__((address_space(3))) void*)(&lds[OP][BUF][(Q)*8192 + d_off]), 16, 0, 0);

// body: 4 A-reads (+4 B-reads if QM==0) || stage issue || 16 x mfma_i32_16x16x64_i8
#define BODY(BUF, QM, ...) do {                                                   \
  _Pragma("unroll") for (int m2 = 0; m2 < 4; ++m2)                                \
    afr[m2] = RD_A(BUF, (QM)*4 + m2);                                             \
  if ((QM) == 0) {                                                                \
    _Pragma("unroll") for (int nf = 0; nf < 4; ++nf)                              \
      bfr[nf] = RD_B(BUF, nf);                                                    \
  }                                                                               \
  __VA_ARGS__                                                                     \
  __builtin_amdgcn_s_setprio(1);                                                  \
  _Pragma("unroll") for (int m2 = 0; m2 < 4; ++m2)                                \
    _Pragma("unroll") for (int nf = 0; nf < 4; ++nf)                              \
      acc[(QM)*4 + m2][nf] = __builtin_amdgcn_mfma_i32_16x16x64_i8(               \
          afr[m2], bfr[nf], acc[(QM)*4 + m2][nf], 0, 0, 0);                       \
  __builtin_amdgcn_s_setprio(0);                                                  \
} while (0)

// ---- 256x256 int8 GEMM, BK=64, 2 blocks/CU: C = A*W^T (i32 exact) ----
__global__ __launch_bounds__(512, 4) void gemm_i8(
    const int8_t* __restrict__ A,   // [M][K] int8
    const int8_t* __restrict__ W,   // [N][K] int8
    const float* __restrict__ sa,   // [M] per-row A scale
    const float* __restrict__ scales,
    const float* __restrict__ bias,
    float* __restrict__ out) {
  __shared__ __attribute__((aligned(16))) char lds[2][2][16384];  // [op][buf]

  const int tid = threadIdx.x;
  const int lane = tid & 63;
  const int wid = tid >> 6;       // 0..7
  const int wm = wid >> 2;        // 0..1 -> 128-row half of A-tile
  const int wn = wid & 3;         // 0..3 -> 64-col quarter of B-tile
  const int l15 = lane & 15;
  const int l4 = lane >> 4;       // 0..3

  // XCD-aware bijective swizzle; m-major within chunk
  const int bid = blockIdx.x;
  const int swz = (bid & 7) * 172 + (bid >> 3);
  const int g = swz / 172;
  const int rem = swz - g * 172;
  const int mq = rem / 43;
  const int mt = g * 4 + mq;          // 0..31
  const int nt = rem - mq * 43;       // 0..42

  // staging: r = tid>>2 (0..127), pos = tid&3; source chunk = pos ^ ((r>>1)&3)
  const int csrc = (tid & 3) ^ ((tid >> 3) & 3);
  const int8_t* a_src = A + ((size_t)(mt * 256 + (tid >> 2))) * K_TOT + csrc * 16;
  const int8_t* b_src = W + ((size_t)(nt * 256 + (tid >> 2))) * K_TOT + csrc * 16;
  const int d_off = tid * 16;   // linear LDS dest

  // fragment reads: row = base + mf*16 + l15, logical chunk l4,
  // phys chunk = l4 ^ ((l15>>1)&3)  (8-lane group covers all 8 bank-quads once)
  const int chunk = l4 ^ ((l15 >> 1) & 3);
  const int va = (wm * 128 + l15) * 64 + chunk * 16;           // A region offset
  const int vb = 32768 + (wn * 64 + l15) * 64 + chunk * 16;    // B absolute offset
  const char* lbase = (const char*)&lds[0][0][0];

  i32x4 acc[8][4];
#pragma unroll
  for (int i = 0; i < 8; ++i)
#pragma unroll
    for (int j = 0; j < 4; ++j) {
      i32x4 z = {0, 0, 0, 0};
      acc[i][j] = z;
    }
  i32x4 afr[4], bfr[4];

  // ---- prologue: A01(0), B01(0) -> buf0 ; A01(1), B01(1) -> buf1 ----
  STG(0, 0, 0, a_src) STG(0, 1, 0, a_src)
  STG(1, 0, 0, b_src) STG(1, 1, 0, b_src)
  STG(0, 0, 1, a_src + 64) STG(0, 1, 1, a_src + 64)
  STG(1, 0, 1, b_src + 64) STG(1, 1, 1, b_src + 64)

  // ---- window 0 (buf0): A01(1)/B01(1) pre-issued; body1 stages B01(2)->buf0 ----
  VM4 BAR
  BODY(0, 0, );
  BAR
  BODY(0, 1, STG(1, 0, 0, b_src + 128) STG(1, 1, 0, b_src + 128));

  // ---- steady: w = 1..60 (30 x 2 windows); invariant outstanding = [B(w),A(w),B(w+1)]
  const int8_t* a_stg = a_src + 2 * 64;   // A01(w+1), first at w=1 -> k-tile 2
  const int8_t* b_stg = b_src + 3 * 64;   // B01(w+2), first at w=1 -> k-tile 3
  for (int it = 0; it < 30; ++it) {
    VM2 BAR
    BODY(1, 0, STG(0, 0, 0, a_stg) STG(0, 1, 0, a_stg));   // A01(w+1) -> buf0
    BAR
    BODY(1, 1, STG(1, 0, 1, b_stg) STG(1, 1, 1, b_stg));   // B01(w+2) -> buf1 (cur)
    a_stg += 64; b_stg += 64;
    VM2 BAR
    BODY(0, 0, STG(0, 0, 1, a_stg) STG(0, 1, 1, a_stg));
    BAR
    BODY(0, 1, STG(1, 0, 0, b_stg) STG(1, 1, 0, b_stg));
    a_stg += 64; b_stg += 64;
  }
  // ---- w=61 (buf1): stage A01(62)->buf0, B01(63)->buf1 ----
  VM2 BAR
  BODY(1, 0, STG(0, 0, 0, a_stg) STG(0, 1, 0, a_stg));
  BAR
  BODY(1, 1, STG(1, 0, 1, b_stg) STG(1, 1, 1, b_stg));
  a_stg += 64;
  // ---- w=62 (buf0): stage A01(63)->buf1; no more B ----
  VM2 BAR
  BODY(0, 0, STG(0, 0, 1, a_stg) STG(0, 1, 1, a_stg));
  BAR
  BODY(0, 1, );
  // ---- w=63 (buf1): drain ----
  VM0 BAR
  BODY(1, 0, );
  BAR
  BODY(1, 1, );

  // ---- epilogue: C/D 16x16: col=l15, row=l4*4+j ----
#pragma unroll
  for (int nf = 0; nf < 4; ++nf) {
    int n_g = nt * 256 + wn * 64 + nf * 16 + l15;
    float s = scales[n_g];
    float b = bias[n_g];
#pragma unroll
    for (int mf = 0; mf < 8; ++mf) {
      int m0 = mt * 256 + wm * 128 + mf * 16 + l4 * 4;
#pragma unroll
      for (int j = 0; j < 4; ++j) {
        int m = m0 + j;
        out[(size_t)m * N_TOT + n_g] = (float)acc[mf][nf][j] * (sa[m] * s) + b;
      }
    }
  }
}

// ---- safety-net fallback if d_ws is too small (slow but correct) ----
__global__ __launch_bounds__(256) void naive_gemm(
    const float* __restrict__ a, const int* __restrict__ w,
    const float* __restrict__ scales, const float* __restrict__ bias,
    float* __restrict__ out) {
  size_t total = (size_t)M_TOT * N_TOT;
  size_t stride = (size_t)gridDim.x * 256;
  for (size_t idx = (size_t)blockIdx.x * 256 + threadIdx.x; idx < total; idx += stride) {
    size_t m = idx / N_TOT, n = idx - m * N_TOT;
    const float* ap = a + m * K_TOT;
    const int* wp = w + n * K_TOT;
    float s = 0.f;
    for (int k = 0; k < K_TOT; ++k) s += ap[k] * (float)wp[k];
    out[idx] = s * scales[n] + bias[n];
  }
}

extern "C" void kernel_launch(void* const* d_in, const int* in_sizes, int n_in,
                              void* d_out, int out_size, void* d_ws, size_t ws_size,
                              hipStream_t stream) {
  const float* inp = (const float*)d_in[0];
  const int* w = (const int*)d_in[1];     // harness widens int8 -> int32
  const float* sc = (const float*)d_in[2];
  const float* bi = (const float*)d_in[3];
  float* out = (float*)d_out;

  const size_t a_elems = (size_t)M_TOT * K_TOT;  // 33.5M
  const size_t w_elems = (size_t)N_TOT * K_TOT;  // 45.1M
  const size_t need = 32768 + a_elems + w_elems;

  if (ws_size >= need) {
    float* ws_sa = (float*)d_ws;
    int8_t* ws_a = (int8_t*)d_ws + 32768;
    int8_t* ws_w = ws_a + a_elems;
    quant_a<<<M_TOT, 256, 0, stream>>>(inp, ws_a, ws_sa);
    pack_w<<<2048, 256, 0, stream>>>(w, ws_w, (int)(w_elems / 16));
    gemm_i8<<<(M_TOT / 256) * (N_TOT / 256), 512, 0, stream>>>(ws_a, ws_w, ws_sa, sc, bi, out);
  } else {
    naive_gemm<<<4096, 256, 0, stream>>>(inp, w, sc, bi, out);
  }
}

// Round 14
// 517.369 us; speedup vs baseline: 6.9076x; 6.9076x over previous
//
#include <hip/hip_runtime.h>
#include <stdint.h>

#define M_TOT 8192
#define K_TOT 4096
#define N_TOT 11008

typedef __attribute__((ext_vector_type(4))) int i32x4;

// ---- pre-pass: A fp32 -> int8 with per-row scale (one block per row) ----
__global__ __launch_bounds__(256) void quant_a(const float* __restrict__ a,
                                               int8_t* __restrict__ o,
                                               float* __restrict__ sa) {
  const int row = blockIdx.x;
  const int tid = threadIdx.x;
  const float* ap = a + (size_t)row * K_TOT + tid * 16;
  float4 v[4];
#pragma unroll
  for (int i = 0; i < 4; ++i) v[i] = *(const float4*)(ap + i * 4);
  float m = 0.f;
#pragma unroll
  for (int i = 0; i < 4; ++i) {
    m = fmaxf(m, fmaxf(fmaxf(fabsf(v[i].x), fabsf(v[i].y)),
                       fmaxf(fabsf(v[i].z), fabsf(v[i].w))));
  }
#pragma unroll
  for (int off = 32; off >= 1; off >>= 1)
    m = fmaxf(m, __shfl_xor(m, off));
  __shared__ float red[4];
  if ((tid & 63) == 0) red[tid >> 6] = m;
  __syncthreads();
  float am = fmaxf(fmaxf(red[0], red[1]), fmaxf(red[2], red[3]));
  float inv = am > 0.f ? 127.0f / am : 0.f;
  if (tid == 0) sa[row] = am > 0.f ? am / 127.0f : 0.f;
  union { int8_t b[16]; int4 q; } rr;
#pragma unroll
  for (int i = 0; i < 4; ++i) {
    float4 w = v[i];
    rr.b[i * 4 + 0] = (int8_t)(int)rintf(w.x * inv);
    rr.b[i * 4 + 1] = (int8_t)(int)rintf(w.y * inv);
    rr.b[i * 4 + 2] = (int8_t)(int)rintf(w.z * inv);
    rr.b[i * 4 + 3] = (int8_t)(int)rintf(w.w * inv);
  }
  *(int4*)(o + (size_t)row * K_TOT + tid * 16) = rr.q;
}

// ---- pre-pass: W int32 (harness widened) -> int8 pack ----
__global__ __launch_bounds__(256) void pack_w(const int* __restrict__ w,
                                              int8_t* __restrict__ o, int n16) {
  int stride = gridDim.x * 256;
  for (int i = blockIdx.x * 256 + threadIdx.x; i < n16; i += stride) {
    const int4* p = (const int4*)(w + (size_t)i * 16);
    int4 v0 = p[0], v1 = p[1], v2 = p[2], v3 = p[3];
    int4 r;
    r.x = (v0.x & 0xff) | ((v0.y & 0xff) << 8) | ((v0.z & 0xff) << 16) | (v0.w << 24);
    r.y = (v1.x & 0xff) | ((v1.y & 0xff) << 8) | ((v1.z & 0xff) << 16) | (v1.w << 24);
    r.z = (v2.x & 0xff) | ((v2.y & 0xff) << 8) | ((v2.z & 0xff) << 16) | (v2.w << 24);
    r.w = (v3.x & 0xff) | ((v3.y & 0xff) << 8) | ((v3.z & 0xff) << 16) | (v3.w << 24);
    *(int4*)(o + (size_t)i * 16) = r;
  }
}

#define VM2 asm volatile("s_waitcnt vmcnt(2)" ::: "memory");
#define VM0 asm volatile("s_waitcnt vmcnt(0)" ::: "memory");
#define BAR __builtin_amdgcn_s_barrier();

// LDS: A [buf][256 x 64B] @0/16384 ; B [buf][128 x 64B] @32768/40960. 48 KiB.
#define RD_A(BUF, MF) (*(const i32x4*)(lbase + ((BUF)*16384 + (MF)*1024) + va))
#define RD_B(BUF, NF) (*(const i32x4*)(lbase + (32768 + (BUF)*8192 + (NF)*1024) + vb))

#define GLDS(SRC, DST) \
  __builtin_amdgcn_global_load_lds( \
      (const __attribute__((address_space(1))) void*)(SRC), \
      (__attribute__((address_space(3))) void*)(DST), 16, 0, 0);

// staging pieces (each 8 KiB = 512 thr x 16 B, dest lane-linear per wave):
//  A_e = rows {0-63,128-191}, A_o = rows {64-127,192-255}, B = rows 0-127
#define STG_AE(BUF, KB) GLDS(ae_src + (KB), lds + (BUF)*16384 + doff_e)
#define STG_AO(BUF, KB) GLDS(ao_src + (KB), lds + (BUF)*16384 + doff_e + 4096)
#define STG_B(BUF, KB)  GLDS(b_src  + (KB), lds + 32768 + (BUF)*8192 + doff_b)

// body: 4 A-frag reads (+2 B if QM==0) || stage issue || 8 x mfma_i32_16x16x64_i8
#define BODY(BUF, QM, ...) do {                                                   \
  _Pragma("unroll") for (int m2 = 0; m2 < 4; ++m2)                                \
    afr[m2] = RD_A(BUF, (QM)*4 + m2);                                             \
  if ((QM) == 0) {                                                                \
    bfr[0] = RD_B(BUF, 0);                                                        \
    bfr[1] = RD_B(BUF, 1);                                                        \
  }                                                                               \
  __VA_ARGS__                                                                     \
  __builtin_amdgcn_s_setprio(1);                                                  \
  _Pragma("unroll") for (int m2 = 0; m2 < 4; ++m2)                                \
    _Pragma("unroll") for (int nf = 0; nf < 2; ++nf)                              \
      acc[(QM)*4 + m2][nf] = __builtin_amdgcn_mfma_i32_16x16x64_i8(               \
          afr[m2], bfr[nf], acc[(QM)*4 + m2][nf], 0, 0, 0);                       \
  __builtin_amdgcn_s_setprio(0);                                                  \
} while (0)

// ---- 256x128 int8 GEMM, BK=64, 2 blocks/CU (regs fit 128/wave) ----
__global__ __launch_bounds__(512, 4) void gemm_i8(
    const int8_t* __restrict__ A,   // [M][K] int8
    const int8_t* __restrict__ W,   // [N][K] int8
    const float* __restrict__ sa,   // [M] per-row A scale
    const float* __restrict__ scales,
    const float* __restrict__ bias,
    float* __restrict__ out) {
  __shared__ __attribute__((aligned(16))) char lds_raw[49152];
  char* lds = lds_raw;

  const int tid = threadIdx.x;
  const int lane = tid & 63;
  const int wid = tid >> 6;       // 0..7
  const int wm = wid >> 2;        // 0..1 -> 128-row half of A-tile
  const int wn = wid & 3;         // 0..3 -> 32-col quarter of B-tile
  const int l15 = lane & 15;
  const int l4 = lane >> 4;       // 0..3

  // XCD-aware bijective swizzle (2752 = 8 x 344); m-major within chunk (4 mt x 86 nt)
  const int bid = blockIdx.x;
  const int swz = (bid & 7) * 344 + (bid >> 3);
  const int g = swz / 344;
  const int rem = swz - g * 344;
  const int mq = rem / 86;
  const int mt = g * 4 + mq;          // 0..31
  const int nt = rem - mq * 86;       // 0..85

  // staging source: row_e = (tid>>2) + (tid>=256 ? 64 : 0); swizzled chunk
  const int row_e = (tid >> 2) + ((tid & 256) ? 64 : 0);
  const int csrc = (tid & 3) ^ ((tid >> 3) & 3);    // pos ^ ((row>>1)&3), row bits 1-2 == (tid>>3)&3
  const int8_t* ae_src = A + ((size_t)(mt * 256 + row_e)) * K_TOT + csrc * 16;
  const int8_t* ao_src = ae_src + (size_t)64 * K_TOT;
  const int8_t* b_src  = W + ((size_t)(nt * 128 + (tid >> 2))) * K_TOT + csrc * 16;
  const int doff_e = row_e * 64 + (tid & 3) * 16;   // lane-linear per wave
  const int doff_b = tid * 16;

  // fragment reads: phys chunk = l4 ^ ((l15>>1)&3); 16-lane group = 2 lanes/bank-quad (free)
  const int chunk = l4 ^ ((l15 >> 1) & 3);
  const int va = (wm * 128 + l15) * 64 + chunk * 16;
  const int vb = (wn * 32 + l15) * 64 + chunk * 16;
  const char* lbase = lds;

  i32x4 acc[8][2];
#pragma unroll
  for (int i = 0; i < 8; ++i)
#pragma unroll
    for (int j = 0; j < 2; ++j) {
      i32x4 z = {0, 0, 0, 0};
      acc[i][j] = z;
    }
  i32x4 afr[4], bfr[2];

  // ---- prologue FIFO: AE(0) B(0) AO(0) AE(1) B(1) ----
  STG_AE(0, 0) STG_B(0, 0) STG_AO(0, 0)
  STG_AE(1, 64) STG_B(1, 64)

  // ---- steady: windows 0..61 (31 x 2); window w: VM2 BAR b0[AO(w+1)->q] BAR b1[AE,B(w+2)->p]
  int kb = 0;   // byte k-offset of tile w
  for (int it = 0; it < 31; ++it) {
    VM2 BAR
    BODY(0, 0, STG_AO(1, kb + 64));
    BAR
    BODY(0, 1, STG_AE(0, kb + 128) STG_B(0, kb + 128));
    VM2 BAR
    BODY(1, 0, STG_AO(0, kb + 128));
    BAR
    BODY(1, 1, STG_AE(1, kb + 192) STG_B(1, kb + 192));
    kb += 128;
  }
  // ---- window 62 (buf0): stage AO(63); nothing else left ----
  VM2 BAR
  BODY(0, 0, STG_AO(1, kb + 64));
  BAR
  BODY(0, 1, );
  // ---- window 63 (buf1): drain ----
  VM0 BAR
  BODY(1, 0, );
  BAR
  BODY(1, 1, );

  // ---- epilogue: C/D 16x16: col=l15, row=l4*4+j ----
#pragma unroll
  for (int nf = 0; nf < 2; ++nf) {
    int n_g = nt * 128 + wn * 32 + nf * 16 + l15;
    float s = scales[n_g];
    float b = bias[n_g];
#pragma unroll
    for (int mf = 0; mf < 8; ++mf) {
      int m0 = mt * 256 + wm * 128 + mf * 16 + l4 * 4;
#pragma unroll
      for (int j = 0; j < 4; ++j) {
        int m = m0 + j;
        out[(size_t)m * N_TOT + n_g] = (float)acc[mf][nf][j] * (sa[m] * s) + b;
      }
    }
  }
}

// ---- safety-net fallback if d_ws is too small (slow but correct) ----
__global__ __launch_bounds__(256) void naive_gemm(
    const float* __restrict__ a, const int* __restrict__ w,
    const float* __restrict__ scales, const float* __restrict__ bias,
    float* __restrict__ out) {
  size_t total = (size_t)M_TOT * N_TOT;
  size_t stride = (size_t)gridDim.x * 256;
  for (size_t idx = (size_t)blockIdx.x * 256 + threadIdx.x; idx < total; idx += stride) {
    size_t m = idx / N_TOT, n = idx - m * N_TOT;
    const float* ap = a + m * K_TOT;
    const int* wp = w + n * K_TOT;
    float s = 0.f;
    for (int k = 0; k < K_TOT; ++k) s += ap[k] * (float)wp[k];
    out[idx] = s * scales[n] + bias[n];
  }
}

extern "C" void kernel_launch(void* const* d_in, const int* in_sizes, int n_in,
                              void* d_out, int out_size, void* d_ws, size_t ws_size,
                              hipStream_t stream) {
  const float* inp = (const float*)d_in[0];
  const int* w = (const int*)d_in[1];     // harness widens int8 -> int32
  const float* sc = (const float*)d_in[2];
  const float* bi = (const float*)d_in[3];
  float* out = (float*)d_out;

  const size_t a_elems = (size_t)M_TOT * K_TOT;  // 33.5M
  const size_t w_elems = (size_t)N_TOT * K_TOT;  // 45.1M
  const size_t need = 32768 + a_elems + w_elems;

  if (ws_size >= need) {
    float* ws_sa = (float*)d_ws;
    int8_t* ws_a = (int8_t*)d_ws + 32768;
    int8_t* ws_w = ws_a + a_elems;
    quant_a<<<M_TOT, 256, 0, stream>>>(inp, ws_a, ws_sa);
    pack_w<<<2048, 256, 0, stream>>>(w, ws_w, (int)(w_elems / 16));
    gemm_i8<<<(M_TOT / 256) * (N_TOT / 128), 512, 0, stream>>>(ws_a, ws_w, ws_sa, sc, bi, out);
  } else {
    naive_gemm<<<4096, 256, 0, stream>>>(inp, w, sc, bi, out);
  }
}

// Round 15
// 491.419 us; speedup vs baseline: 7.2724x; 1.0528x over previous
//
#include <hip/hip_runtime.h>
#include <stdint.h>

#define M_TOT 8192
#define K_TOT 4096
#define N_TOT 11008
#define BM 256
#define BN 256
#define BK 128
#define NT2 32

typedef __attribute__((ext_vector_type(4))) int i32x4;
typedef __attribute__((ext_vector_type(16))) int i32x16;

// ---- pre-pass: A fp32 -> int8 with per-row scale (one block per row) ----
__global__ __launch_bounds__(256) void quant_a(const float* __restrict__ a,
                                               int8_t* __restrict__ o,
                                               float* __restrict__ sa) {
  const int row = blockIdx.x;
  const int tid = threadIdx.x;
  const float* ap = a + (size_t)row * K_TOT + tid * 16;
  float4 v[4];
#pragma unroll
  for (int i = 0; i < 4; ++i) v[i] = *(const float4*)(ap + i * 4);
  float m = 0.f;
#pragma unroll
  for (int i = 0; i < 4; ++i) {
    m = fmaxf(m, fmaxf(fmaxf(fabsf(v[i].x), fabsf(v[i].y)),
                       fmaxf(fabsf(v[i].z), fabsf(v[i].w))));
  }
#pragma unroll
  for (int off = 32; off >= 1; off >>= 1)
    m = fmaxf(m, __shfl_xor(m, off));
  __shared__ float red[4];
  if ((tid & 63) == 0) red[tid >> 6] = m;
  __syncthreads();
  float am = fmaxf(fmaxf(red[0], red[1]), fmaxf(red[2], red[3]));
  float inv = am > 0.f ? 127.0f / am : 0.f;
  if (tid == 0) sa[row] = am > 0.f ? am / 127.0f : 0.f;
  union { int8_t b[16]; int4 q; } rr;
#pragma unroll
  for (int i = 0; i < 4; ++i) {
    float4 w = v[i];
    rr.b[i * 4 + 0] = (int8_t)(int)rintf(w.x * inv);
    rr.b[i * 4 + 1] = (int8_t)(int)rintf(w.y * inv);
    rr.b[i * 4 + 2] = (int8_t)(int)rintf(w.z * inv);
    rr.b[i * 4 + 3] = (int8_t)(int)rintf(w.w * inv);
  }
  *(int4*)(o + (size_t)row * K_TOT + tid * 16) = rr.q;
}

// ---- pre-pass: W int32 (harness widened) -> int8 pack ----
__global__ __launch_bounds__(256) void pack_w(const int* __restrict__ w,
                                              int8_t* __restrict__ o, int n16) {
  int stride = gridDim.x * 256;
  for (int i = blockIdx.x * 256 + threadIdx.x; i < n16; i += stride) {
    const int4* p = (const int4*)(w + (size_t)i * 16);
    int4 v0 = p[0], v1 = p[1], v2 = p[2], v3 = p[3];
    int4 r;
    r.x = (v0.x & 0xff) | ((v0.y & 0xff) << 8) | ((v0.z & 0xff) << 16) | (v0.w << 24);
    r.y = (v1.x & 0xff) | ((v1.y & 0xff) << 8) | ((v1.z & 0xff) << 16) | (v1.w << 24);
    r.z = (v2.x & 0xff) | ((v2.y & 0xff) << 8) | ((v2.z & 0xff) << 16) | (v2.w << 24);
    r.w = (v3.x & 0xff) | ((v3.y & 0xff) << 8) | ((v3.z & 0xff) << 16) | (v3.w << 24);
    *(int4*)(o + (size_t)i * 16) = r;
  }
}

#define VM6 asm volatile("s_waitcnt vmcnt(6)" ::: "memory");
#define VM4 asm volatile("s_waitcnt vmcnt(4)" ::: "memory");
#define VM0 asm volatile("s_waitcnt vmcnt(0)" ::: "memory");
#define BAR __builtin_amdgcn_s_barrier();

// LDS layout: [op 0=A,1=B][buf][256 rows x 128 B] ; all indices below literal.
#define RD_A(BUF, QM, M2, KS) \
  (*(const i32x4*)(lbase + ((BUF)*32768 + (QM)*8192 + (M2)*4096) + va[KS]))
#define RD_B(BUF, NF, KS) \
  (*(const i32x4*)(lbase + ((BUF)*32768 + (NF)*4096) + vb[KS]))

#define STG(OP, Q, BUF, SRC) \
  __builtin_amdgcn_global_load_lds( \
      (const __attribute__((address_space(1))) void*)((SRC) + (size_t)(Q)*64*K_TOT), \
      (__attribute__((address_space(3))) void*)(&lds[OP][BUF][(Q)*8192 + d_off]), 16, 0, 0);

// One body: ds_read block || stage issue || 16 MFMA (32x32x32 i8), 4 indep acc chains
#define BODY(BUF, QM, ...) do {                                                   \
  _Pragma("unroll") for (int m2 = 0; m2 < 2; ++m2)                                \
    _Pragma("unroll") for (int ks = 0; ks < 4; ++ks)                              \
      afr[m2][ks] = RD_A(BUF, QM, m2, ks);                                        \
  if ((QM) == 0) {                                                                \
    _Pragma("unroll") for (int nf = 0; nf < 2; ++nf)                              \
      _Pragma("unroll") for (int ks = 0; ks < 4; ++ks)                            \
        bfr[nf][ks] = RD_B(BUF, nf, ks);                                          \
  }                                                                               \
  __VA_ARGS__                                                                     \
  __builtin_amdgcn_s_setprio(1);                                                  \
  _Pragma("unroll") for (int ks = 0; ks < 4; ++ks)                                \
    _Pragma("unroll") for (int m2 = 0; m2 < 2; ++m2)                              \
      _Pragma("unroll") for (int nf = 0; nf < 2; ++nf)                            \
        acc[(QM)*2 + m2][nf] = __builtin_amdgcn_mfma_i32_32x32x32_i8(             \
            afr[m2][ks], bfr[nf][ks], acc[(QM)*2 + m2][nf], 0, 0, 0);             \
  __builtin_amdgcn_s_setprio(0);                                                  \
} while (0)

// ---- 256x256 int8 GEMM, 32x32x32 MFMA, R5 structure + m-fastest XCD chunk ----
__global__ __launch_bounds__(512, 2) void gemm_i8(
    const int8_t* __restrict__ A,   // [M][K] int8
    const int8_t* __restrict__ W,   // [N][K] int8
    const float* __restrict__ sa,   // [M] per-row A scale
    const float* __restrict__ scales,
    const float* __restrict__ bias,
    float* __restrict__ out) {
  __shared__ __attribute__((aligned(16))) char lds[2][2][32768];  // [op][buf]

  const int tid = threadIdx.x;
  const int lane = tid & 63;
  const int wid = tid >> 6;       // 0..7
  const int wm = wid >> 2;        // 0..1 -> 128-row half of A-tile
  const int wn = wid & 3;         // 0..3 -> 64-col quarter of B-tile
  const int l31 = lane & 31;
  const int hi = lane >> 5;       // 0..1

  // XCD-aware bijective swizzle; M-FASTEST within chunk (groups of 4 share a B panel;
  // the same 4 A panels stay L2-hot across the whole 172-block chunk)
  const int bid = blockIdx.x;
  const int swz = (bid & 7) * 172 + (bid >> 3);
  const int g = swz / 172;
  const int rem = swz - g * 172;
  const int mq = rem & 3;             // m fastest
  const int mt = g * 4 + mq;          // 0..31
  const int nt = rem >> 2;            // 0..42

  // staging: 512 threads stage one 64-row x 128B quarter (16B/lane)
  // full 3-bit XOR pre-swizzle (R5-proven): LDS pos p of row r holds logical chunk p^(r&7)
  const int r = tid >> 3;                    // 0..63
  const int csrc = (tid & 7) ^ (r & 7);      // pre-swizzled source chunk
  const int8_t* a_src = A + ((size_t)(mt * 256 + r)) * K_TOT + csrc * 16;
  const int8_t* b_src = W + ((size_t)(nt * 256 + r)) * K_TOT + csrc * 16;
  const int d_off = r * 128 + (tid & 7) * 16;   // linear LDS dest

  // fragment read vaddrs: logical chunk (ks*2+hi) of row l31 -> phys = (ks*2+hi)^(l31&7)
  int va[4], vb[4];
#pragma unroll
  for (int ks = 0; ks < 4; ++ks) {
    int phys = ((ks * 2 + hi) ^ (l31 & 7)) * 16;
    va[ks] = (wm * 128 + l31) * 128 + phys;          // A-op region offset
    vb[ks] = 65536 + (wn * 64 + l31) * 128 + phys;   // B-op absolute offset
  }
  const char* lbase = (const char*)&lds[0][0][0];

  i32x16 acc[4][2];
#pragma unroll
  for (int i = 0; i < 4; ++i)
#pragma unroll
    for (int j = 0; j < 2; ++j)
#pragma unroll
      for (int e = 0; e < 16; ++e) acc[i][j][e] = 0;
  i32x4 afr[2][4], bfr[2][4];

  // ---- prologue: issue tile0 fully + A02(1) ----
  STG(0, 0, 0, a_src) STG(0, 2, 0, a_src)            // A02(0)
  STG(1, 0, 0, b_src) STG(1, 1, 0, b_src)            // B01(0)
  STG(1, 2, 0, b_src) STG(1, 3, 0, b_src)            // B23(0)
  STG(0, 1, 0, a_src) STG(0, 3, 0, a_src)            // A13(0)
  STG(0, 0, 1, a_src + 128) STG(0, 2, 1, a_src + 128)  // A02(1)
  const int8_t* a_nxt = a_src + 128;
  const int8_t* b_nxt = b_src + 128;

  // ---- steady: 15 x 2 windows, buffers literal ----
  for (int it = 0; it < 15; ++it) {
    VM4 BAR
    BODY(0, 0, STG(1, 0, 1, b_nxt) STG(1, 1, 1, b_nxt)
               STG(1, 2, 1, b_nxt) STG(1, 3, 1, b_nxt));
    VM6 BAR
    BODY(0, 1, STG(0, 1, 1, a_nxt) STG(0, 3, 1, a_nxt)
               STG(0, 0, 0, a_nxt + 128) STG(0, 2, 0, a_nxt + 128));
    a_nxt += 128; b_nxt += 128;
    VM4 BAR
    BODY(1, 0, STG(1, 0, 0, b_nxt) STG(1, 1, 0, b_nxt)
               STG(1, 2, 0, b_nxt) STG(1, 3, 0, b_nxt));
    VM6 BAR
    BODY(1, 1, STG(0, 1, 0, a_nxt) STG(0, 3, 0, a_nxt)
               STG(0, 0, 1, a_nxt + 128) STG(0, 2, 1, a_nxt + 128));
    a_nxt += 128; b_nxt += 128;
  }
  // ---- window 30: stage only tile 31 pieces ----
  VM4 BAR
  BODY(0, 0, STG(1, 0, 1, b_nxt) STG(1, 1, 1, b_nxt)
             STG(1, 2, 1, b_nxt) STG(1, 3, 1, b_nxt));
  VM6 BAR
  BODY(0, 1, STG(0, 1, 1, a_nxt) STG(0, 3, 1, a_nxt));
  // ---- window 31: drain ----
  VM0 BAR
  BODY(1, 0, );
  BODY(1, 1, );

  // ---- epilogue: C/D 32x32: col=l31, row=(reg&3)+8*(reg>>2)+4*hi ----
  const int ng0 = nt * 256 + wn * 64 + l31;
  const float s0 = scales[ng0], s1 = scales[ng0 + 32];
  const float b0 = bias[ng0], b1 = bias[ng0 + 32];
#pragma unroll
  for (int mf = 0; mf < 4; ++mf) {
    int mb = mt * 256 + wm * 128 + mf * 32 + hi * 4;
#pragma unroll
    for (int reg = 0; reg < 16; ++reg) {
      int m = mb + (reg & 3) + 8 * (reg >> 2);
      float sm = sa[m];
      float* row = out + (size_t)m * N_TOT;
      row[ng0] = (float)acc[mf][0][reg] * (sm * s0) + b0;
      row[ng0 + 32] = (float)acc[mf][1][reg] * (sm * s1) + b1;
    }
  }
}

// ---- safety-net fallback if d_ws is too small (slow but correct) ----
__global__ __launch_bounds__(256) void naive_gemm(
    const float* __restrict__ a, const int* __restrict__ w,
    const float* __restrict__ scales, const float* __restrict__ bias,
    float* __restrict__ out) {
  size_t total = (size_t)M_TOT * N_TOT;
  size_t stride = (size_t)gridDim.x * 256;
  for (size_t idx = (size_t)blockIdx.x * 256 + threadIdx.x; idx < total; idx += stride) {
    size_t m = idx / N_TOT, n = idx - m * N_TOT;
    const float* ap = a + m * K_TOT;
    const int* wp = w + n * K_TOT;
    float s = 0.f;
    for (int k = 0; k < K_TOT; ++k) s += ap[k] * (float)wp[k];
    out[idx] = s * scales[n] + bias[n];
  }
}

extern "C" void kernel_launch(void* const* d_in, const int* in_sizes, int n_in,
                              void* d_out, int out_size, void* d_ws, size_t ws_size,
                              hipStream_t stream) {
  const float* inp = (const float*)d_in[0];
  const int* w = (const int*)d_in[1];     // harness widens int8 -> int32
  const float* sc = (const float*)d_in[2];
  const float* bi = (const float*)d_in[3];
  float* out = (float*)d_out;

  const size_t a_elems = (size_t)M_TOT * K_TOT;  // 33.5M
  const size_t w_elems = (size_t)N_TOT * K_TOT;  // 45.1M
  const size_t need = 32768 + a_elems + w_elems;

  if (ws_size >= need) {
    float* ws_sa = (float*)d_ws;
    int8_t* ws_a = (int8_t*)d_ws + 32768;
    int8_t* ws_w = ws_a + a_elems;
    quant_a<<<M_TOT, 256, 0, stream>>>(inp, ws_a, ws_sa);
    pack_w<<<2048, 256, 0, stream>>>(w, ws_w, (int)(w_elems / 16));
    gemm_i8<<<(M_TOT / BM) * (N_TOT / BN), 512, 0, stream>>>(ws_a, ws_w, ws_sa, sc, bi, out);
  } else {
    naive_gemm<<<4096, 256, 0, stream>>>(inp, w, sc, bi, out);
  }
}

// Round 18
// 488.404 us; speedup vs baseline: 7.3173x; 1.0062x over previous
//
#include <hip/hip_runtime.h>
#include <stdint.h>

#define M_TOT 8192
#define K_TOT 4096
#define N_TOT 11008
#define BM 256
#define BN 256
#define BK 128

typedef __attribute__((ext_vector_type(4))) int i32x4;

// ---- pre-pass: A fp32 -> int8 with per-row scale (one block per row) ----
__global__ __launch_bounds__(256) void quant_a(const float* __restrict__ a,
                                               int8_t* __restrict__ o,
                                               float* __restrict__ sa) {
  const int row = blockIdx.x;
  const int tid = threadIdx.x;
  const float* ap = a + (size_t)row * K_TOT + tid * 16;
  float4 v[4];
#pragma unroll
  for (int i = 0; i < 4; ++i) v[i] = *(const float4*)(ap + i * 4);
  float m = 0.f;
#pragma unroll
  for (int i = 0; i < 4; ++i) {
    m = fmaxf(m, fmaxf(fmaxf(fabsf(v[i].x), fabsf(v[i].y)),
                       fmaxf(fabsf(v[i].z), fabsf(v[i].w))));
  }
#pragma unroll
  for (int off = 32; off >= 1; off >>= 1)
    m = fmaxf(m, __shfl_xor(m, off));
  __shared__ float red[4];
  if ((tid & 63) == 0) red[tid >> 6] = m;
  __syncthreads();
  float am = fmaxf(fmaxf(red[0], red[1]), fmaxf(red[2], red[3]));
  float inv = am > 0.f ? 127.0f / am : 0.f;
  if (tid == 0) sa[row] = am > 0.f ? am / 127.0f : 0.f;
  union { int8_t b[16]; int4 q; } rr;
#pragma unroll
  for (int i = 0; i < 4; ++i) {
    float4 w = v[i];
    rr.b[i * 4 + 0] = (int8_t)(int)rintf(w.x * inv);
    rr.b[i * 4 + 1] = (int8_t)(int)rintf(w.y * inv);
    rr.b[i * 4 + 2] = (int8_t)(int)rintf(w.z * inv);
    rr.b[i * 4 + 3] = (int8_t)(int)rintf(w.w * inv);
  }
  *(int4*)(o + (size_t)row * K_TOT + tid * 16) = rr.q;
}

// ---- pre-pass: W int32 (harness widened) -> int8 pack ----
__global__ __launch_bounds__(256) void pack_w(const int* __restrict__ w,
                                              int8_t* __restrict__ o, int n16) {
  int stride = gridDim.x * 256;
  for (int i = blockIdx.x * 256 + threadIdx.x; i < n16; i += stride) {
    const int4* p = (const int4*)(w + (size_t)i * 16);
    int4 v0 = p[0], v1 = p[1], v2 = p[2], v3 = p[3];
    int4 r;
    r.x = (v0.x & 0xff) | ((v0.y & 0xff) << 8) | ((v0.z & 0xff) << 16) | (v0.w << 24);
    r.y = (v1.x & 0xff) | ((v1.y & 0xff) << 8) | ((v1.z & 0xff) << 16) | (v1.w << 24);
    r.z = (v2.x & 0xff) | ((v2.y & 0xff) << 8) | ((v2.z & 0xff) << 16) | (v2.w << 24);
    r.w = (v3.x & 0xff) | ((v3.y & 0xff) << 8) | ((v3.z & 0xff) << 16) | (v3.w << 24);
    *(int4*)(o + (size_t)i * 16) = r;
  }
}

#define VM2 asm volatile("s_waitcnt vmcnt(2)" ::: "memory");
#define VM0 asm volatile("s_waitcnt vmcnt(0)" ::: "memory");
#define BAR __builtin_amdgcn_s_barrier();
#define SCHED0 __builtin_amdgcn_sched_barrier(0);

// LDS flat 128 KiB: A op@0, B op@65536; per op: [buf][256 rows x 128B]
#define RD_A(BUF, QM, MF, KS) \
  (*(const i32x4*)(lbase + ((BUF)*32768 + (QM)*8192 + (MF)*2048) + aoff[KS]))
#define RD_B(BUF, J, KS) \
  (*(const i32x4*)(lbase + (65536 + (BUF)*32768 + (J)*2048) + boff[KS]))

#define STG(OP, Q, BUF, SRC) \
  __builtin_amdgcn_global_load_lds( \
      (const __attribute__((address_space(1))) void*)((SRC) + (size_t)(Q)*64*K_TOT), \
      (__attribute__((address_space(3))) void*)(lds + (OP)*65536 + (BUF)*32768 + (Q)*8192 + d_off), 16, 0, 0);

// One window, SINGLE barrier: VM2 then BAR (collective landing for the 8 DMAs
// VM2 drains = all of tile w, staged by ALL waves — vmcnt is per-wave, so the
// barrier after it is what makes the guarantee chip-wide; R16/R17 read before
// this barrier and raced) -> 24 ds_reads -> B/A13(w+1) stages (buf^1, disjoint)
// -> 64 MFMA -> A02(w+2) into current buf q0/2 (disjoint from a1's q1/3; a0's
// q0/2 reads drained ~350cy post-BAR, DMA issues >=900cy post-BAR).
#define WINDOW(BUF, VMW, STGB, STGA13, STGA02) do {                               \
  VMW                                                                             \
  BAR                                                                             \
  _Pragma("unroll") for (int mf = 0; mf < 4; ++mf) {                              \
    a0[mf][0] = RD_A(BUF, 0, mf, 0);                                              \
    a0[mf][1] = RD_A(BUF, 0, mf, 1);                                              \
  }                                                                               \
  _Pragma("unroll") for (int j = 0; j < 4; ++j) {                                 \
    bb[j][0] = RD_B(BUF, j, 0);                                                   \
    bb[j][1] = RD_B(BUF, j, 1);                                                   \
  }                                                                               \
  _Pragma("unroll") for (int mf = 0; mf < 4; ++mf) {                              \
    a1[mf][0] = RD_A(BUF, 1, mf, 0);                                              \
    a1[mf][1] = RD_A(BUF, 1, mf, 1);                                              \
  }                                                                               \
  STGB                                                                            \
  STGA13                                                                          \
  __builtin_amdgcn_s_setprio(1);                                                  \
  _Pragma("unroll") for (int ks = 0; ks < 2; ++ks)                                \
    _Pragma("unroll") for (int mf = 0; mf < 4; ++mf)                              \
      _Pragma("unroll") for (int j = 0; j < 4; ++j)                               \
        acc[mf][j] = __builtin_amdgcn_mfma_i32_16x16x64_i8(                       \
            a0[mf][ks], bb[j][ks], acc[mf][j], 0, 0, 0);                          \
  _Pragma("unroll") for (int ks = 0; ks < 2; ++ks)                                \
    _Pragma("unroll") for (int mf = 0; mf < 4; ++mf)                              \
      _Pragma("unroll") for (int j = 0; j < 4; ++j)                               \
        acc[4 + mf][j] = __builtin_amdgcn_mfma_i32_16x16x64_i8(                   \
            a1[mf][ks], bb[j][ks], acc[4 + mf][j], 0, 0, 0);                      \
  __builtin_amdgcn_s_setprio(0);                                                  \
  SCHED0                                                                          \
  STGA02                                                                          \
} while (0)

// ---- 256x256 int8 GEMM: single-barrier windows, VM2 ledger ----
__global__ __launch_bounds__(512) void gemm_i8(
    const int8_t* __restrict__ A,   // [M][K] int8
    const int8_t* __restrict__ W,   // [N][K] int8
    const float* __restrict__ sa,   // [M] per-row A scale
    const float* __restrict__ scales,
    const float* __restrict__ bias,
    float* __restrict__ out) {
  __shared__ __attribute__((aligned(16))) char lds[131072];

  const int tid = threadIdx.x;
  const int lane = tid & 63;
  const int wid = tid >> 6;       // 0..7
  const int wm = wid >> 2;        // 0..1 -> 128-row half of A-tile
  const int wn = wid & 3;         // 0..3 -> 64-col quarter of B-tile
  const int l15 = lane & 15;
  const int l4 = lane >> 4;       // 0..3

  // XCD-aware bijective swizzle; m-fastest within chunk (R15: FETCH -63%)
  const int bid = blockIdx.x;
  const int swz = (bid & 7) * 172 + (bid >> 3);
  const int g = swz / 172;
  const int rem = swz - g * 172;
  const int mq = rem & 3;             // m fastest
  const int mt = g * 4 + mq;          // 0..31
  const int nt = rem >> 2;            // 0..42

  // staging: 512 threads stage one 64-row x 128B quarter (16B/lane)
  // full 3-bit XOR pre-swizzle (R5-proven, 0 conflicts)
  const int r = tid >> 3;                    // 0..63
  const int csrc = (tid & 7) ^ (r & 7);      // pre-swizzled source chunk
  const int8_t* a_src = A + ((size_t)(mt * 256 + r)) * K_TOT + csrc * 16;
  const int8_t* b_src = W + ((size_t)(nt * 256 + r)) * K_TOT + csrc * 16;
  const int d_off = r * 128 + (tid & 7) * 16;   // linear LDS dest

  // fragment read offsets: logical chunk (l4, l4^4) -> phys = logical ^ (l15&7)
  const int xm = l15 & 7;
  const int pc0 = l4 ^ xm;
  const int pc1 = pc0 ^ 4;
  int aoff[2], boff[2];
  aoff[0] = (wm * 128 + l15) * 128 + pc0 * 16;
  aoff[1] = (wm * 128 + l15) * 128 + pc1 * 16;
  boff[0] = (wn * 64 + l15) * 128 + pc0 * 16;
  boff[1] = (wn * 64 + l15) * 128 + pc1 * 16;
  const char* lbase = lds;

  i32x4 acc[8][4];
#pragma unroll
  for (int i = 0; i < 8; ++i)
#pragma unroll
    for (int j = 0; j < 4; ++j) {
      i32x4 z = {0, 0, 0, 0};
      acc[i][j] = z;
    }
  i32x4 a0[4][2], a1[4][2], bb[4][2];

  // ---- prologue: A02(0), B(0) x4, A13(0), A02(1) = 10 issues ----
  STG(0, 0, 0, a_src) STG(0, 2, 0, a_src)
  STG(1, 0, 0, b_src) STG(1, 1, 0, b_src) STG(1, 2, 0, b_src) STG(1, 3, 0, b_src)
  STG(0, 1, 0, a_src) STG(0, 3, 0, a_src)
  STG(0, 0, 1, a_src + 128) STG(0, 2, 1, a_src + 128)
  const int8_t* a_nxt = a_src + 128;
  const int8_t* b_nxt = b_src + 128;

  // ---- steady: windows 0..29 (15 x 2); FIFO per window: B(w+1), A13(w+1), A02(w+2)
  for (int it = 0; it < 15; ++it) {
    WINDOW(0, VM2,
        STG(1, 0, 1, b_nxt) STG(1, 1, 1, b_nxt) STG(1, 2, 1, b_nxt) STG(1, 3, 1, b_nxt),
        STG(0, 1, 1, a_nxt) STG(0, 3, 1, a_nxt),
        STG(0, 0, 0, a_nxt + 128) STG(0, 2, 0, a_nxt + 128));
    a_nxt += 128; b_nxt += 128;
    WINDOW(1, VM2,
        STG(1, 0, 0, b_nxt) STG(1, 1, 0, b_nxt) STG(1, 2, 0, b_nxt) STG(1, 3, 0, b_nxt),
        STG(0, 1, 0, a_nxt) STG(0, 3, 0, a_nxt),
        STG(0, 0, 1, a_nxt + 128) STG(0, 2, 1, a_nxt + 128));
    a_nxt += 128; b_nxt += 128;
  }
  // ---- window 30: stage B(31), A13(31); no A02 left ----
  WINDOW(0, VM2,
      STG(1, 0, 1, b_nxt) STG(1, 1, 1, b_nxt) STG(1, 2, 1, b_nxt) STG(1, 3, 1, b_nxt),
      STG(0, 1, 1, a_nxt) STG(0, 3, 1, a_nxt),
      );
  // ---- window 31: drain ----
  WINDOW(1, VM0, , , );

  // ---- epilogue: C/D 16x16: col=l15, row=l4*4+jj ----
#pragma unroll
  for (int j = 0; j < 4; ++j) {
    int n_g = nt * 256 + wn * 64 + j * 16 + l15;
    float s = scales[n_g];
    float b = bias[n_g];
#pragma unroll
    for (int i = 0; i < 8; ++i) {
      int m0 = mt * 256 + wm * 128 + i * 16 + l4 * 4;
#pragma unroll
      for (int jj = 0; jj < 4; ++jj) {
        int m = m0 + jj;
        out[(size_t)m * N_TOT + n_g] = (float)acc[i][j][jj] * (sa[m] * s) + b;
      }
    }
  }
}

// ---- safety-net fallback if d_ws is too small (slow but correct) ----
__global__ __launch_bounds__(256) void naive_gemm(
    const float* __restrict__ a, const int* __restrict__ w,
    const float* __restrict__ scales, const float* __restrict__ bias,
    float* __restrict__ out) {
  size_t total = (size_t)M_TOT * N_TOT;
  size_t stride = (size_t)gridDim.x * 256;
  for (size_t idx = (size_t)blockIdx.x * 256 + threadIdx.x; idx < total; idx += stride) {
    size_t m = idx / N_TOT, n = idx - m * N_TOT;
    const float* ap = a + m * K_TOT;
    const int* wp = w + n * K_TOT;
    float s = 0.f;
    for (int k = 0; k < K_TOT; ++k) s += ap[k] * (float)wp[k];
    out[idx] = s * scales[n] + bias[n];
  }
}

extern "C" void kernel_launch(void* const* d_in, const int* in_sizes, int n_in,
                              void* d_out, int out_size, void* d_ws, size_t ws_size,
                              hipStream_t stream) {
  const float* inp = (const float*)d_in[0];
  const int* w = (const int*)d_in[1];     // harness widens int8 -> int32
  const float* sc = (const float*)d_in[2];
  const float* bi = (const float*)d_in[3];
  float* out = (float*)d_out;

  const size_t a_elems = (size_t)M_TOT * K_TOT;  // 33.5M
  const size_t w_elems = (size_t)N_TOT * K_TOT;  // 45.1M
  const size_t need = 32768 + a_elems + w_elems;

  if (ws_size >= need) {
    float* ws_sa = (float*)d_ws;
    int8_t* ws_a = (int8_t*)d_ws + 32768;
    int8_t* ws_w = ws_a + a_elems;
    quant_a<<<M_TOT, 256, 0, stream>>>(inp, ws_a, ws_sa);
    pack_w<<<2048, 256, 0, stream>>>(w, ws_w, (int)(w_elems / 16));
    gemm_i8<<<(M_TOT / BM) * (N_TOT / BN), 512, 0, stream>>>(ws_a, ws_w, ws_sa, sc, bi, out);
  } else {
    naive_gemm<<<4096, 256, 0, stream>>>(inp, w, sc, bi, out);
  }
}